// Round 2
// baseline (550.843 us; speedup 1.0000x reference)
//
#include <hip/hip_runtime.h>
#include <cstdint>
#include <cstddef>

typedef unsigned short u16;
typedef __attribute__((ext_vector_type(8))) short bf16x8;
typedef __attribute__((ext_vector_type(4))) float f32x4;

#define MFMA32(a, b, c) __builtin_amdgcn_mfma_f32_16x16x32_bf16(a, b, c, 0, 0, 0)

__device__ __forceinline__ u16 f2b(float f) {
  union { float f; unsigned u; } v; v.f = f;
  unsigned u = v.u;
  return (u16)((u + 0x7fffu + ((u >> 16) & 1u)) >> 16);
}
__device__ __forceinline__ float b2f(u16 h) {
  union { unsigned u; float f; } v; v.u = ((unsigned)h) << 16;
  return v.f;
}

// async global->LDS, 16B per lane. LDS dest must be wave-uniform base + lane*16.
__device__ __forceinline__ void g2l16(const void* g, void* l) {
  __builtin_amdgcn_global_load_lds((__attribute__((address_space(1))) void*)(g),
                                   (__attribute__((address_space(3))) void*)(l), 16, 0, 0);
}

// ---------------- fp32 -> bf16 cast (vectorized x4) ----------------
__global__ __launch_bounds__(256) void cast_f2b_v4(const float* __restrict__ in,
                                                   u16* __restrict__ out, int n4) {
  int i = blockIdx.x * 256 + threadIdx.x;
  if (i >= n4) return;
  float4 v = ((const float4*)in)[i];
  ushort4 r;
  r.x = f2b(v.x); r.y = f2b(v.y); r.z = f2b(v.z); r.w = f2b(v.w);
  ((ushort4*)out)[i] = r;
}

// ---------------- C = A @ B^T  128x128 tile (m97 structure, kept for final proj)
template <bool BF16_OUT>
__global__ __launch_bounds__(256) void gemm_bt(const u16* __restrict__ A,
                                               const u16* __restrict__ B,
                                               void* __restrict__ C, int N, int K) {
  __shared__ u16 As[128 * 64];
  __shared__ u16 Bs[128 * 64];
  const int tid = threadIdx.x;
  const int wid = tid >> 6;
  const int lane = tid & 63;
  const int lm = lane & 15;
  const int quad = lane >> 4;
  const int r3 = lm & 7;
  const int wm = (wid & 1) * 64;
  const int wn = (wid >> 1) * 64;
  const int bm = blockIdx.y * 128;
  const int bn = blockIdx.x * 128;

  const u16* Ab = A + (size_t)bm * K;
  const u16* Bb = B + (size_t)bn * K;

  f32x4 zero = {0.f, 0.f, 0.f, 0.f};
  f32x4 acc[4][4];
#pragma unroll
  for (int i = 0; i < 4; ++i)
#pragma unroll
    for (int j = 0; j < 4; ++j) acc[i][j] = zero;

  for (int k0 = 0; k0 < K; k0 += 64) {
#pragma unroll
    for (int it = 0; it < 4; ++it) {
      int c = it * 256 + tid;
      int rg = c >> 6, rw = (c >> 3) & 7, u = c & 7;
      int row = rg * 8 + rw;
      int chd = u ^ rw;  // store chunk (row, chd) at linear chunk c
      g2l16(Ab + (size_t)row * K + k0 + chd * 8, As + c * 8);
      g2l16(Bb + (size_t)row * K + k0 + chd * 8, Bs + c * 8);
    }
    __syncthreads();
#pragma unroll
    for (int ks = 0; ks < 2; ++ks) {
      bf16x8 a[4], b[4];
      int chd = ks * 4 + quad;
#pragma unroll
      for (int i = 0; i < 4; ++i) {
        int row = wm + i * 16 + lm;  // row&7 == r3
        a[i] = *(const bf16x8*)(As + (((row >> 3) * 64 + r3 * 8 + (chd ^ r3)) * 8));
      }
#pragma unroll
      for (int j = 0; j < 4; ++j) {
        int row = wn + j * 16 + lm;
        b[j] = *(const bf16x8*)(Bs + (((row >> 3) * 64 + r3 * 8 + (chd ^ r3)) * 8));
      }
#pragma unroll
      for (int i = 0; i < 4; ++i)
#pragma unroll
        for (int j = 0; j < 4; ++j)
          acc[i][j] = MFMA32(a[i], b[j], acc[i][j]);
    }
    __syncthreads();
  }

#pragma unroll
  for (int i = 0; i < 4; ++i)
#pragma unroll
    for (int j = 0; j < 4; ++j)
#pragma unroll
      for (int r = 0; r < 4; ++r) {
        int row = bm + wm + i * 16 + quad * 4 + r;
        int col = bn + wn + j * 16 + lm;
        float v = acc[i][j][r];
        if (BF16_OUT)
          ((u16*)C)[(size_t)row * N + col] = f2b(v);
        else
          ((float*)C)[(size_t)row * N + col] = v;
      }
}

// ---------------- C = A @ B^T  256x256 tile, 8-phase counted-vmcnt schedule ----
// T3+T4 template: BK=64, 8 waves (2Mx4N, 128x64 per wave), 128KiB LDS
// (2 bufs x {A,B} x 2 halves x 128x64 bf16), XOR-chunk swizzle (T2),
// s_setprio around MFMA clusters (T5).
// Phase plan per iter (2 K-tiles: even tile in buf0, odd in buf1):
//   ph j=0: ds_read ALL 24 frags of buf0; MFMA quad (0,0)
//   ph j=1..3: MFMA quads (0,1),(1,0),(1,1)
//   ph j=4: ds_read all frags of buf1; MFMA quad (0,0); j=5..7 rest
// Stage queue: 1 half-tile per phase from j such that p=8i+j-1 >= 0:
//   tile = 2+(p>>2), half p&3 (h0=A.lo,h1=A.hi,h2=B.lo,h3=B.hi).
//   -> buf0 of next pair staged at ph1..4 (after buf0's reads done at ph0-end),
//      buf1 at ph5..7 + next iter ph0.
// Waits: vmcnt(6) at ph3/ph7 end = allow 3 newest half-tiles (6 loads) in
// flight; everything older (the buffer about to be read) is complete.
// Final iter: vmcnt(0) (its h3 stage has no younger loads to count against).
__global__ __launch_bounds__(512) void gemm_bt_256(const u16* __restrict__ A,
                                                   const u16* __restrict__ B,
                                                   u16* __restrict__ C, int N, int K) {
  extern __shared__ char smem[];
  u16* sA = (u16*)smem;            // 4 x 16KiB halves: (buf*2+half)*8192 u16
  u16* sB = (u16*)(smem + 65536);  // same layout
  const int tid = threadIdx.x;
  const int wid = tid >> 6, lane = tid & 63;
  const int lm = lane & 15, quad = lane >> 4, rx = lm & 7;
  const int wm = wid >> 2;      // 0..1  (M half)
  const int wn = wid & 3;       // 0..3  (N quarter)
  const int bm = blockIdx.y * 256;
  const int bn = blockIdx.x * 256;

  const u16* Ablk = A + (size_t)bm * K;
  const u16* Bblk = B + (size_t)bn * K;

  f32x4 zero = {0.f, 0.f, 0.f, 0.f};
  f32x4 acc[8][4];
#pragma unroll
  for (int i = 0; i < 8; ++i)
#pragma unroll
    for (int j = 0; j < 4; ++j) acc[i][j] = zero;

  bf16x8 aA[8][2];  // 8 M-frags x 2 k-slices of current buffer
  bf16x8 bB[4][2];  // 4 N-frags x 2 k-slices

  // stage one half-tile (128 rows x 64 k) of tile st into its buffer slot.
  auto stageh = [&](int st, int sh) {
    const int k0 = st << 6;
    const int b = st & 1;
    const u16* src;
    u16* dst;
    int rowbase;
    if (sh < 2) { src = Ablk; rowbase = sh << 7; dst = sA + (b * 2 + sh) * 8192; }
    else        { src = Bblk; rowbase = (sh - 2) << 7; dst = sB + (b * 2 + (sh - 2)) * 8192; }
#pragma unroll
    for (int it = 0; it < 2; ++it) {
      const int c = it * 512 + tid;
      const int r = c >> 3, u = c & 7;
      // LDS chunk c=(r, u) receives global chunk (r, u^(r&7))  [XOR involution]
      g2l16(src + (size_t)(rowbase + r) * K + k0 + ((u ^ (r & 7)) << 3), dst + (size_t)c * 8);
    }
  };

  auto readfrags = [&](int hb) {
    const u16* Ah = sA + (hb * 2 + wm) * 8192;
    const u16* Bh = sB + (hb * 2 + (wn >> 1)) * 8192;
#pragma unroll
    for (int ii = 0; ii < 8; ++ii)
#pragma unroll
      for (int ks = 0; ks < 2; ++ks)
        aA[ii][ks] = *(const bf16x8*)(Ah + (((ii * 16 + lm) * 8 + ((ks * 4 + quad) ^ rx)) << 3));
#pragma unroll
    for (int jj = 0; jj < 4; ++jj)
#pragma unroll
      for (int ks = 0; ks < 2; ++ks)
        bB[jj][ks] = *(const bf16x8*)(Bh + ((((wn & 1) * 64 + jj * 16 + lm) * 8 +
                                             ((ks * 4 + quad) ^ rx)) << 3));
  };

  const int NT = K >> 6;    // 64-wide K tiles (even; pairs of tiles per iter)
  const int NIT = NT >> 1;

  // prologue: stage tiles 0 and 1 fully (8 halves, 16 loads/thread)
#pragma unroll
  for (int s = 0; s < 8; ++s) stageh(s >> 2, s & 3);
  asm volatile("s_waitcnt vmcnt(8)" ::: "memory");  // tile0 complete; tile1 in flight
  __builtin_amdgcn_s_barrier();

#pragma unroll 1
  for (int i = 0; i < NIT; ++i) {
#pragma unroll
    for (int j = 0; j < 8; ++j) {
      if (j == 0) readfrags(0);
      if (j == 4) readfrags(1);
      {
        const int p = 8 * i + j - 1;
        if (p >= 0) {
          const int st = 2 + (p >> 2);
          if (st < NT) stageh(st, p & 3);
        }
      }
      __builtin_amdgcn_s_barrier();
      if (j == 0 || j == 4) asm volatile("s_waitcnt lgkmcnt(0)" ::: "memory");
      __builtin_amdgcn_s_setprio(1);
      const int mh = (j >> 1) & 1, nh = j & 1;
#pragma unroll
      for (int ii = 0; ii < 4; ++ii)
#pragma unroll
        for (int jj = 0; jj < 2; ++jj)
#pragma unroll
          for (int ks = 0; ks < 2; ++ks)
            acc[mh * 4 + ii][nh * 2 + jj] =
                MFMA32(aA[mh * 4 + ii][ks], bB[nh * 2 + jj][ks], acc[mh * 4 + ii][nh * 2 + jj]);
      __builtin_amdgcn_s_setprio(0);
      if (j == 3 || j == 7) {
        if (i + 1 == NIT) asm volatile("s_waitcnt vmcnt(0)" ::: "memory");
        else              asm volatile("s_waitcnt vmcnt(6)" ::: "memory");
      }
      __builtin_amdgcn_s_barrier();
    }
  }

  // epilogue
#pragma unroll
  for (int ii = 0; ii < 8; ++ii)
#pragma unroll
    for (int jj = 0; jj < 4; ++jj)
#pragma unroll
      for (int r = 0; r < 4; ++r) {
        const int row = bm + wm * 128 + ii * 16 + quad * 4 + r;
        const int col = bn + wn * 64 + jj * 16 + lm;
        C[(size_t)row * N + col] = f2b(acc[ii][jj][r]);
      }
}

// ---------------- RoPE + head rearrange (R1-proven, + Q pre-scale) ------------
// Y: (B*S, 6144) cols = [q_sem(1024) | k_sem(1024) | q_geo(1024) | k_geo(1024) | v(2048)]
// Q,K: (B*H, S, 128)   VT: (B*H, 128, S).  Q scaled by (1/sqrt(128))*log2(e).
__global__ __launch_bounds__(256) void rope_rearrange(const u16* __restrict__ Y,
                                                      u16* __restrict__ Q,
                                                      u16* __restrict__ Kb,
                                                      u16* __restrict__ VT) {
  const float SC = 0.12751744f;  // (1/sqrt(128)) * log2(e)
  const int idx = blockIdx.x * 256 + threadIdx.x;  // over B*S*2048
  const int c = idx & 2047;
  const int bs = idx >> 11;
  const int s = bs & 2047;
  const int h = c >> 7;
  const int d = c & 127;
  const u16* Yr = Y + (size_t)bs * 6144;
  const size_t bh = (size_t)(bs >> 11) * 16 + h;

  // V (transposed store)
  VT[(bh * 128 + d) * 2048 + s] = Yr[4096 + c];

  float qv, kv;
  if (d < 64) {
    qv = b2f(Yr[h * 64 + d]);
    kv = b2f(Yr[1024 + h * 64 + d]);
  } else {
    int dg = d - 64;
    int f0 = dg & 31;
    float inv = __powf(10000.0f, -(float)(2 * f0) * (1.0f / 64.0f));
    float ang = (float)s * inv;
    float sn = sinf(ang), cs = cosf(ang);
    float qx1 = b2f(Yr[2048 + h * 64 + f0]);
    float qx2 = b2f(Yr[2048 + h * 64 + f0 + 32]);
    float kx1 = b2f(Yr[3072 + h * 64 + f0]);
    float kx2 = b2f(Yr[3072 + h * 64 + f0 + 32]);
    if (dg < 32) { qv = qx1 * cs - qx2 * sn; kv = kx1 * cs - kx2 * sn; }
    else         { qv = qx1 * sn + qx2 * cs; kv = kx1 * sn + kx2 * cs; }
  }
  size_t qo = (bh * 2048 + s) * 128 + d;
  Q[qo] = f2b(qv * SC);
  Kb[qo] = f2b(kv);
}

// ---------------- fused causal attention v5 (R1-passed: T2 swizzle) -----------
__global__ __launch_bounds__(256, 3) void attn_v4(const u16* __restrict__ Q,
                                                  const u16* __restrict__ K,
                                                  const u16* __restrict__ VT,
                                                  u16* __restrict__ O) {
  constexpr int S = 2048;
  constexpr int D = 128;
  __shared__ u16 Ks[64 * 128];
  __shared__ u16 Vs[128 * 64];  // VT tile: [d][s_local], chunk-swizzled
  __shared__ u16 Ps[64 * 72];   // padded stride 72 (144B rows, 16B-aligned)
  const int bx = blockIdx.x;
  const int bh = blockIdx.y;
  const int b = bh >> 4, h = bh & 15;
  const int tid = threadIdx.x, wid = tid >> 6, lane = tid & 63;
  const int lm = lane & 15, quad = lane >> 4;
  const int rx = lm & 7;  // == row&7 for every fragment row this lane reads
  const int wrow = wid * 16;

#pragma unroll 1
  for (int pass = 0; pass < 2; ++pass) {
    const int qt = pass == 0 ? bx : 31 - bx;

    // Q A-operand fragments direct from global
    bf16x8 aq[4];
#pragma unroll
    for (int ks = 0; ks < 4; ++ks)
      aq[ks] = *(const bf16x8*)(Q + ((size_t)bh * S + (size_t)qt * 64 + wrow + lm) * D +
                                ks * 32 + quad * 8);

    float l_r[4] = {0.f, 0.f, 0.f, 0.f};
    f32x4 zero = {0.f, 0.f, 0.f, 0.f};
    f32x4 oacc[8];
#pragma unroll
    for (int t = 0; t < 8; ++t) oacc[t] = zero;

    for (int kt = 0; kt <= qt; ++kt) {
      __syncthreads();  // protect Ks/Vs/Ps from prior iteration's readers
      const u16* Kt = K + ((size_t)bh * S + (size_t)kt * 64) * D;
#pragma unroll
      for (int it = 0; it < 4; ++it) {
        int c = it * 256 + tid;
        int row = c >> 4, u = c & 15;
        g2l16(Kt + (size_t)row * 128 + (size_t)(u ^ (row & 7)) * 8, Ks + c * 8);
      }
      const u16* Vt = VT + (size_t)bh * D * S + (size_t)kt * 64;
#pragma unroll
      for (int it = 0; it < 4; ++it) {
        int c = it * 256 + tid;
        int row = c >> 3, u = c & 7;
        g2l16(Vt + (size_t)row * S + (size_t)(u ^ (row & 7)) * 8, Vs + c * 8);
      }
      __syncthreads();

      // S-tile = Q K^T : wave rows wrow..wrow+15, 64 cols
      f32x4 sc[4];
#pragma unroll
      for (int j = 0; j < 4; ++j) sc[j] = zero;
#pragma unroll
      for (int ks = 0; ks < 4; ++ks) {
        const int kc = ks * 4 + quad;
#pragma unroll
        for (int j = 0; j < 4; ++j) {
          bf16x8 bk = *(const bf16x8*)(Ks + (((j * 16 + lm) * 16 + (kc ^ rx)) * 8));
          sc[j] = MFMA32(aq[ks], bk, sc[j]);
        }
      }

      const bool diag = (kt == qt);
#pragma unroll
      for (int r = 0; r < 4; ++r) {
        const int qcol = wrow + quad * 4 + r;  // q row within this 64-tile
        float pv[4];
        float rs = 0.f;
#pragma unroll
        for (int j = 0; j < 4; ++j) {
          float p = __builtin_amdgcn_exp2f(fminf(sc[j][r], 30.0f));
          if (diag && (j * 16 + lm > qcol)) p = 0.f;
          rs += p;
          pv[j] = p;
        }
#pragma unroll
        for (int dd = 1; dd < 16; dd <<= 1) rs += __shfl_xor(rs, dd);
        l_r[r] += rs;
        const int prow = (wrow + quad * 4 + r) * 72;
#pragma unroll
        for (int j = 0; j < 4; ++j) Ps[prow + j * 16 + lm] = f2b(pv[j]);
      }
      __syncthreads();  // P visible to all waves

      // O += P @ V : P (64x64, stride 72) as A, Vs ([d][s], swizzled) as B
#pragma unroll
      for (int ks = 0; ks < 2; ++ks) {
        bf16x8 ap = *(const bf16x8*)(Ps + (wrow + lm) * 72 + ks * 32 + quad * 8);
        const int kc = ks * 4 + quad;
#pragma unroll
        for (int t = 0; t < 8; ++t) {
          bf16x8 bv = *(const bf16x8*)(Vs + (((t * 16 + lm) * 8 + (kc ^ rx)) * 8));
          oacc[t] = MFMA32(ap, bv, oacc[t]);
        }
      }
    }

    // epilogue: O row = b*S + s, col = h*128 + d  (bf16)
#pragma unroll
    for (int r = 0; r < 4; ++r) {
      float inv = 1.0f / l_r[r];
      const int srow = qt * 64 + wrow + quad * 4 + r;
      u16* Orow = O + ((size_t)b * S + srow) * 2048 + h * 128;
#pragma unroll
      for (int t = 0; t < 8; ++t) Orow[t * 16 + lm] = f2b(oacc[t][r] * inv);
    }
  }
}

extern "C" void kernel_launch(void* const* d_in, const int* in_sizes, int n_in,
                              void* d_out, int out_size, void* d_ws, size_t ws_size,
                              hipStream_t stream) {
  const float* x      = (const float*)d_in[0];
  const float* Wq_sem = (const float*)d_in[1];
  const float* Wk_sem = (const float*)d_in[2];
  const float* Wq_geo = (const float*)d_in[3];
  const float* Wk_geo = (const float*)d_in[4];
  const float* Wv     = (const float*)d_in[5];
  const float* Wo     = (const float*)d_in[6];

  char* ws = (char*)d_ws;
  // layout (bytes):
  //   [0, 16M)          xb  (x bf16, 4096x2048)        -> later reused as Q
  //   [16M, 41.2M)      Wall (6144x2048 bf16)          -> later reused as O
  //   [41.2M, 49.6M)    Wob  (2048x2048 bf16)
  //   [49.6M, 99.9M)    Y    (4096x6144 bf16)
  // d_out (33.5MB) used as scratch for K (16.7M) + VT (16.7M) until final GEMM.
  u16* xb   = (u16*)(ws);
  u16* Wall = (u16*)(ws + 16777216);
  u16* Wob  = (u16*)(ws + 16777216 + 25165824);
  u16* Y    = (u16*)(ws + 16777216 + 25165824 + 8388608);
  u16* Qb   = xb;
  u16* Ob   = Wall;
  u16* Kb   = (u16*)d_out;
  u16* VT   = (u16*)((char*)d_out + 16777216);

  // allow 128 KiB dynamic LDS for the 8-phase GEMM
  hipFuncSetAttribute((const void*)gemm_bt_256,
                      hipFuncAttributeMaxDynamicSharedMemorySize, 131072);

  // casts to bf16
  cast_f2b_v4<<<8192, 256, 0, stream>>>(x, xb, 2097152);
  cast_f2b_v4<<<2048, 256, 0, stream>>>(Wq_sem, Wall + 0 * 2097152, 524288);
  cast_f2b_v4<<<2048, 256, 0, stream>>>(Wk_sem, Wall + 1 * 2097152, 524288);
  cast_f2b_v4<<<2048, 256, 0, stream>>>(Wq_geo, Wall + 2 * 2097152, 524288);
  cast_f2b_v4<<<2048, 256, 0, stream>>>(Wk_geo, Wall + 3 * 2097152, 524288);
  cast_f2b_v4<<<4096, 256, 0, stream>>>(Wv,     Wall + 4 * 2097152, 1048576);
  cast_f2b_v4<<<4096, 256, 0, stream>>>(Wo, Wob, 1048576);

  // fused QKV projection: Y = x @ Wall^T   (M=4096, N=6144, K=2048), 8-phase 256²
  gemm_bt_256<<<dim3(24, 16), 512, 131072, stream>>>(xb, Wall, Y, 6144, 2048);

  // RoPE + head split/rearrange (Q pre-scaled by 1/sqrt(128)*log2e)
  rope_rearrange<<<32768, 256, 0, stream>>>(Y, Qb, Kb, VT);

  // causal flash attention -> O (B*S, 2048) bf16
  attn_v4<<<dim3(16, 32), 256, 0, stream>>>(Qb, Kb, VT, Ob);

  // final projection: out = O @ Wo^T  (M=4096, N=2048, K=2048), fp32 out
  gemm_bt<false><<<dim3(16, 32), 256, 0, stream>>>(Ob, Wob, d_out, 2048, 2048);
}

// Round 3
// 411.970 us; speedup vs baseline: 1.3371x; 1.3371x over previous
//
#include <hip/hip_runtime.h>
#include <cstdint>
#include <cstddef>

typedef unsigned short u16;
typedef __attribute__((ext_vector_type(8))) short bf16x8;
typedef __attribute__((ext_vector_type(4))) float f32x4;

#define MFMA32(a, b, c) __builtin_amdgcn_mfma_f32_16x16x32_bf16(a, b, c, 0, 0, 0)

__device__ __forceinline__ u16 f2b(float f) {
  union { float f; unsigned u; } v; v.f = f;
  unsigned u = v.u;
  return (u16)((u + 0x7fffu + ((u >> 16) & 1u)) >> 16);
}
__device__ __forceinline__ float b2f(u16 h) {
  union { unsigned u; float f; } v; v.u = ((unsigned)h) << 16;
  return v.f;
}

// async global->LDS, 16B per lane. LDS dest must be wave-uniform base + lane*16.
__device__ __forceinline__ void g2l16(const void* g, void* l) {
  __builtin_amdgcn_global_load_lds((__attribute__((address_space(1))) void*)(g),
                                   (__attribute__((address_space(3))) void*)(l), 16, 0, 0);
}

// ---------------- fp32 -> bf16 cast (vectorized x4) ----------------
__global__ __launch_bounds__(256) void cast_f2b_v4(const float* __restrict__ in,
                                                   u16* __restrict__ out, int n4) {
  int i = blockIdx.x * 256 + threadIdx.x;
  if (i >= n4) return;
  float4 v = ((const float4*)in)[i];
  ushort4 r;
  r.x = f2b(v.x); r.y = f2b(v.y); r.z = f2b(v.z); r.w = f2b(v.w);
  ((ushort4*)out)[i] = r;
}

// ---------------- C = A @ B^T   (A: MxK bf16, B: NxK bf16, both K-major) ------
// 128x128 tile, BK=64, 4 waves (2x2), 4x4 MFMA/wave. XOR-chunk-swizzled LDS.
// (Proven structure; the 256² 8-phase port regressed 2x in R2 — reverted.)
template <bool BF16_OUT>
__global__ __launch_bounds__(256) void gemm_bt(const u16* __restrict__ A,
                                               const u16* __restrict__ B,
                                               void* __restrict__ C, int N, int K) {
  __shared__ u16 As[128 * 64];
  __shared__ u16 Bs[128 * 64];
  const int tid = threadIdx.x;
  const int wid = tid >> 6;
  const int lane = tid & 63;
  const int lm = lane & 15;
  const int quad = lane >> 4;
  const int r3 = lm & 7;
  const int wm = (wid & 1) * 64;
  const int wn = (wid >> 1) * 64;
  const int bm = blockIdx.y * 128;
  const int bn = blockIdx.x * 128;

  const u16* Ab = A + (size_t)bm * K;
  const u16* Bb = B + (size_t)bn * K;

  f32x4 zero = {0.f, 0.f, 0.f, 0.f};
  f32x4 acc[4][4];
#pragma unroll
  for (int i = 0; i < 4; ++i)
#pragma unroll
    for (int j = 0; j < 4; ++j) acc[i][j] = zero;

  for (int k0 = 0; k0 < K; k0 += 64) {
#pragma unroll
    for (int it = 0; it < 4; ++it) {
      int c = it * 256 + tid;
      int rg = c >> 6, rw = (c >> 3) & 7, u = c & 7;
      int row = rg * 8 + rw;
      int chd = u ^ rw;  // store chunk (row, chd) at linear chunk c
      g2l16(Ab + (size_t)row * K + k0 + chd * 8, As + c * 8);
      g2l16(Bb + (size_t)row * K + k0 + chd * 8, Bs + c * 8);
    }
    __syncthreads();
#pragma unroll
    for (int ks = 0; ks < 2; ++ks) {
      bf16x8 a[4], b[4];
      int chd = ks * 4 + quad;
#pragma unroll
      for (int i = 0; i < 4; ++i) {
        int row = wm + i * 16 + lm;  // row&7 == r3
        a[i] = *(const bf16x8*)(As + (((row >> 3) * 64 + r3 * 8 + (chd ^ r3)) * 8));
      }
#pragma unroll
      for (int j = 0; j < 4; ++j) {
        int row = wn + j * 16 + lm;
        b[j] = *(const bf16x8*)(Bs + (((row >> 3) * 64 + r3 * 8 + (chd ^ r3)) * 8));
      }
#pragma unroll
      for (int i = 0; i < 4; ++i)
#pragma unroll
        for (int j = 0; j < 4; ++j)
          acc[i][j] = MFMA32(a[i], b[j], acc[i][j]);
    }
    __syncthreads();
  }

#pragma unroll
  for (int i = 0; i < 4; ++i)
#pragma unroll
    for (int j = 0; j < 4; ++j)
#pragma unroll
      for (int r = 0; r < 4; ++r) {
        int row = bm + wm + i * 16 + quad * 4 + r;
        int col = bn + wn + j * 16 + lm;
        float v = acc[i][j][r];
        if (BF16_OUT)
          ((u16*)C)[(size_t)row * N + col] = f2b(v);
        else
          ((float*)C)[(size_t)row * N + col] = v;
      }
}

// ---------------- RoPE + head rearrange v2: coalesced VT via LDS transpose ----
// Y: (B*S, 6144) cols = [q_sem(1024) | k_sem(1024) | q_geo(1024) | k_geo(1024) | v(2048)]
// Q,K: (B*H, S, 128)   VT: (B*H, 128, S).  Q scaled by (1/sqrt(128))*log2(e).
// Old version scattered VT as 2B stores 4KB apart (up to ~32x write amplification).
// v2: block = (s-tile of 64, bh); V staged in LDS [d][sl] (stride 68, conflict-
// light), then written as ushort4 rows (coalesced). __powf hoisted (d fixed/thread).
__global__ __launch_bounds__(256) void rope_rearrange_v2(const u16* __restrict__ Y,
                                                         u16* __restrict__ Q,
                                                         u16* __restrict__ Kb,
                                                         u16* __restrict__ VT) {
  const float SC = 0.12751744f;  // (1/sqrt(128)) * log2(e)
  __shared__ u16 T[128][68];     // V tile: [d][s_local], padded stride
  const int st = blockIdx.x;     // s-tile (64 rows)
  const int bh = blockIdx.y;     // b*16 + h
  const int b = bh >> 4, h = bh & 15;
  const int tid = threadIdx.x;
  const int d = tid & 127;
  const int sgrp = tid >> 7;  // 0/1

  // hoisted rope frequency (depends only on d)
  float inv = 0.f;
  const int f0 = d & 31;
  if (d >= 64) inv = __powf(10000.0f, -(float)(2 * f0) * (1.0f / 64.0f));

  const u16* Yc = Y + (size_t)(b * 2048 + st * 64) * 6144;

#pragma unroll 4
  for (int k = 0; k < 32; ++k) {
    const int sl = sgrp * 32 + k;
    const int s = st * 64 + sl;
    const u16* Yr = Yc + (size_t)sl * 6144;

    // V -> LDS tile (global read coalesced along d)
    T[d][sl] = Yr[4096 + h * 128 + d];

    float qv, kv;
    if (d < 64) {
      qv = b2f(Yr[h * 64 + d]);
      kv = b2f(Yr[1024 + h * 64 + d]);
    } else {
      float ang = (float)s * inv;
      float sn = sinf(ang), cs = cosf(ang);
      float qx1 = b2f(Yr[2048 + h * 64 + f0]);
      float qx2 = b2f(Yr[2048 + h * 64 + f0 + 32]);
      float kx1 = b2f(Yr[3072 + h * 64 + f0]);
      float kx2 = b2f(Yr[3072 + h * 64 + f0 + 32]);
      if (d < 96) { qv = qx1 * cs - qx2 * sn; kv = kx1 * cs - kx2 * sn; }
      else        { qv = qx1 * sn + qx2 * cs; kv = kx1 * sn + kx2 * cs; }
    }
    size_t qo = ((size_t)bh * 2048 + s) * 128 + d;
    Q[qo] = f2b(qv * SC);
    Kb[qo] = f2b(kv);
  }
  __syncthreads();

  // VT write: row dd gets 64 consecutive s (128B), as ushort4 (8B/lane, coalesced)
#pragma unroll
  for (int it = 0; it < 8; ++it) {
    const int i = it * 256 + tid;
    const int dd = i >> 4;      // 0..127
    const int ch = i & 15;      // 16 x ushort4 per row
    ushort4 v = *(const ushort4*)(&T[dd][ch * 4]);
    *(ushort4*)(VT + ((size_t)bh * 128 + dd) * 2048 + st * 64 + ch * 4) = v;
  }
}

// ---------------- fused causal attention v5 (R1 T2 swizzle + T5 setprio) ------
__global__ __launch_bounds__(256, 3) void attn_v4(const u16* __restrict__ Q,
                                                  const u16* __restrict__ K,
                                                  const u16* __restrict__ VT,
                                                  u16* __restrict__ O) {
  constexpr int S = 2048;
  constexpr int D = 128;
  __shared__ u16 Ks[64 * 128];
  __shared__ u16 Vs[128 * 64];  // VT tile: [d][s_local], chunk-swizzled
  __shared__ u16 Ps[64 * 72];   // padded stride 72 (144B rows, 16B-aligned)
  const int bx = blockIdx.x;
  const int bh = blockIdx.y;
  const int b = bh >> 4, h = bh & 15;
  const int tid = threadIdx.x, wid = tid >> 6, lane = tid & 63;
  const int lm = lane & 15, quad = lane >> 4;
  const int rx = lm & 7;  // == row&7 for every fragment row this lane reads
  const int wrow = wid * 16;

#pragma unroll 1
  for (int pass = 0; pass < 2; ++pass) {
    const int qt = pass == 0 ? bx : 31 - bx;

    // Q A-operand fragments direct from global
    bf16x8 aq[4];
#pragma unroll
    for (int ks = 0; ks < 4; ++ks)
      aq[ks] = *(const bf16x8*)(Q + ((size_t)bh * S + (size_t)qt * 64 + wrow + lm) * D +
                                ks * 32 + quad * 8);

    float l_r[4] = {0.f, 0.f, 0.f, 0.f};
    f32x4 zero = {0.f, 0.f, 0.f, 0.f};
    f32x4 oacc[8];
#pragma unroll
    for (int t = 0; t < 8; ++t) oacc[t] = zero;

    for (int kt = 0; kt <= qt; ++kt) {
      __syncthreads();  // protect Ks/Vs/Ps from prior iteration's readers
      const u16* Kt = K + ((size_t)bh * S + (size_t)kt * 64) * D;
#pragma unroll
      for (int it = 0; it < 4; ++it) {
        int c = it * 256 + tid;
        int row = c >> 4, u = c & 15;
        g2l16(Kt + (size_t)row * 128 + (size_t)(u ^ (row & 7)) * 8, Ks + c * 8);
      }
      const u16* Vt = VT + (size_t)bh * D * S + (size_t)kt * 64;
#pragma unroll
      for (int it = 0; it < 4; ++it) {
        int c = it * 256 + tid;
        int row = c >> 3, u = c & 7;
        g2l16(Vt + (size_t)row * S + (size_t)(u ^ (row & 7)) * 8, Vs + c * 8);
      }
      __syncthreads();

      // S-tile = Q K^T : wave rows wrow..wrow+15, 64 cols
      f32x4 sc[4];
#pragma unroll
      for (int j = 0; j < 4; ++j) sc[j] = zero;
      __builtin_amdgcn_s_setprio(1);
#pragma unroll
      for (int ks = 0; ks < 4; ++ks) {
        const int kc = ks * 4 + quad;
#pragma unroll
        for (int j = 0; j < 4; ++j) {
          bf16x8 bk = *(const bf16x8*)(Ks + (((j * 16 + lm) * 16 + (kc ^ rx)) * 8));
          sc[j] = MFMA32(aq[ks], bk, sc[j]);
        }
      }
      __builtin_amdgcn_s_setprio(0);

      const bool diag = (kt == qt);
#pragma unroll
      for (int r = 0; r < 4; ++r) {
        const int qcol = wrow + quad * 4 + r;  // q row within this 64-tile
        float pv[4];
        float rs = 0.f;
#pragma unroll
        for (int j = 0; j < 4; ++j) {
          float p = __builtin_amdgcn_exp2f(fminf(sc[j][r], 30.0f));
          if (diag && (j * 16 + lm > qcol)) p = 0.f;
          rs += p;
          pv[j] = p;
        }
#pragma unroll
        for (int dd = 1; dd < 16; dd <<= 1) rs += __shfl_xor(rs, dd);
        l_r[r] += rs;
        const int prow = (wrow + quad * 4 + r) * 72;
#pragma unroll
        for (int j = 0; j < 4; ++j) Ps[prow + j * 16 + lm] = f2b(pv[j]);
      }
      __syncthreads();  // P visible to all waves

      // O += P @ V : P (64x64, stride 72) as A, Vs ([d][s], swizzled) as B
      __builtin_amdgcn_s_setprio(1);
#pragma unroll
      for (int ks = 0; ks < 2; ++ks) {
        bf16x8 ap = *(const bf16x8*)(Ps + (wrow + lm) * 72 + ks * 32 + quad * 8);
        const int kc = ks * 4 + quad;
#pragma unroll
        for (int t = 0; t < 8; ++t) {
          bf16x8 bv = *(const bf16x8*)(Vs + (((t * 16 + lm) * 8 + (kc ^ rx)) * 8));
          oacc[t] = MFMA32(ap, bv, oacc[t]);
        }
      }
      __builtin_amdgcn_s_setprio(0);
    }

    // epilogue: O row = b*S + s, col = h*128 + d  (bf16)
#pragma unroll
    for (int r = 0; r < 4; ++r) {
      float inv = 1.0f / l_r[r];
      const int srow = qt * 64 + wrow + quad * 4 + r;
      u16* Orow = O + ((size_t)b * S + srow) * 2048 + h * 128;
#pragma unroll
      for (int t = 0; t < 8; ++t) Orow[t * 16 + lm] = f2b(oacc[t][r] * inv);
    }
  }
}

extern "C" void kernel_launch(void* const* d_in, const int* in_sizes, int n_in,
                              void* d_out, int out_size, void* d_ws, size_t ws_size,
                              hipStream_t stream) {
  const float* x      = (const float*)d_in[0];
  const float* Wq_sem = (const float*)d_in[1];
  const float* Wk_sem = (const float*)d_in[2];
  const float* Wq_geo = (const float*)d_in[3];
  const float* Wk_geo = (const float*)d_in[4];
  const float* Wv     = (const float*)d_in[5];
  const float* Wo     = (const float*)d_in[6];

  char* ws = (char*)d_ws;
  // layout (bytes):
  //   [0, 16M)          xb  (x bf16, 4096x2048)        -> later reused as Q
  //   [16M, 41.2M)      Wall (6144x2048 bf16)          -> later reused as O
  //   [41.2M, 49.6M)    Wob  (2048x2048 bf16)
  //   [49.6M, 99.9M)    Y    (4096x6144 bf16)
  // d_out (33.5MB) used as scratch for K (16.7M) + VT (16.7M) until final GEMM.
  u16* xb   = (u16*)(ws);
  u16* Wall = (u16*)(ws + 16777216);
  u16* Wob  = (u16*)(ws + 16777216 + 25165824);
  u16* Y    = (u16*)(ws + 16777216 + 25165824 + 8388608);
  u16* Qb   = xb;
  u16* Ob   = Wall;
  u16* Kb   = (u16*)d_out;
  u16* VT   = (u16*)((char*)d_out + 16777216);

  // casts to bf16
  cast_f2b_v4<<<8192, 256, 0, stream>>>(x, xb, 2097152);
  cast_f2b_v4<<<2048, 256, 0, stream>>>(Wq_sem, Wall + 0 * 2097152, 524288);
  cast_f2b_v4<<<2048, 256, 0, stream>>>(Wk_sem, Wall + 1 * 2097152, 524288);
  cast_f2b_v4<<<2048, 256, 0, stream>>>(Wq_geo, Wall + 2 * 2097152, 524288);
  cast_f2b_v4<<<2048, 256, 0, stream>>>(Wk_geo, Wall + 3 * 2097152, 524288);
  cast_f2b_v4<<<4096, 256, 0, stream>>>(Wv,     Wall + 4 * 2097152, 1048576);
  cast_f2b_v4<<<4096, 256, 0, stream>>>(Wo, Wob, 1048576);

  // fused QKV projection: Y = x @ Wall^T   (M=4096, N=6144, K=2048)
  gemm_bt<true><<<dim3(48, 32), 256, 0, stream>>>(xb, Wall, Y, 6144, 2048);

  // RoPE + head split/rearrange (Q pre-scaled by 1/sqrt(128)*log2e)
  rope_rearrange_v2<<<dim3(32, 32), 256, 0, stream>>>(Y, Qb, Kb, VT);

  // causal flash attention -> O (B*S, 2048) bf16
  attn_v4<<<dim3(16, 32), 256, 0, stream>>>(Qb, Kb, VT, Ob);

  // final projection: out = O @ Wo^T  (M=4096, N=2048, K=2048), fp32 out
  gemm_bt<false><<<dim3(16, 32), 256, 0, stream>>>(Ob, Wob, d_out, 2048, 2048);
}